// Round 11
// baseline (105.389 us; speedup 1.0000x reference)
//
#include <hip/hip_runtime.h>
#include <hip/hip_bf16.h>

#define B_ 16
#define SQ_ 2048
#define SK_ 2048
#define D_ 64
#define DV_ 64
#define INV_KEEP 1.1111111f  /* 1/(1-0.1) */
#define QSCALE 0.1803368801f /* 0.125 * log2(e): QK^T yields s*log2e; exp2 gives exp(s) */

typedef float f4 __attribute__((ext_vector_type(4)));
typedef __bf16 bf16x2 __attribute__((ext_vector_type(2)));
typedef __bf16 bf16x8 __attribute__((ext_vector_type(8)));
typedef short s16x4 __attribute__((ext_vector_type(4)));
typedef unsigned int u32;
typedef unsigned int u32x2 __attribute__((ext_vector_type(2)));
typedef unsigned int u32x4 __attribute__((ext_vector_type(4)));

// manual f32 -> bf16 RNE (prep kernels)
static __device__ __forceinline__ unsigned short bf16u(float f) {
    u32 u = __builtin_bit_cast(u32, f);
    u += 0x7fffu + ((u >> 16) & 1u);
    return (unsigned short)(u >> 16);
}
static __device__ __forceinline__ u32 pk2(float lo, float hi) {
    return (u32)bf16u(lo) | ((u32)bf16u(hi) << 16);
}
// hot-path pack: compiler emits v_cvt_pk_bf16_f32
static __device__ __forceinline__ u32 pkc(float lo, float hi) {
    bf16x2 t = {(__bf16)lo, (__bf16)hi};
    return __builtin_bit_cast(u32, t);
}

static __device__ __forceinline__ float fexp2(float x) {
#if __has_builtin(__builtin_amdgcn_exp2f)
    return __builtin_amdgcn_exp2f(x);
#else
    return exp2f(x);
#endif
}

// volatile-asm register loads: pinned in program order, can't be sunk/reordered
template <int OFF>
static __device__ __forceinline__ f4 gload_f4(const float* p) {
    f4 d;
    if constexpr (OFF == 0)
        asm volatile("global_load_dwordx4 %0, %1, off" : "=v"(d) : "v"(p));
    else
        asm volatile("global_load_dwordx4 %0, %1, off offset:%2" : "=v"(d) : "v"(p), "i"(OFF));
    return d;
}
template <int OFF>
static __device__ __forceinline__ u32x4 gload_u4(const unsigned short* p) {
    u32x4 d;
    if constexpr (OFF == 0)
        asm volatile("global_load_dwordx4 %0, %1, off" : "=v"(d) : "v"(p));
    else
        asm volatile("global_load_dwordx4 %0, %1, off offset:%2" : "=v"(d) : "v"(p), "i"(OFF));
    return d;
}

static __device__ __forceinline__ f4 mfma16(s16x4 a, s16x4 b, f4 c) {
#if __has_builtin(__builtin_amdgcn_mfma_f32_16x16x16bf16_1k)
    return __builtin_amdgcn_mfma_f32_16x16x16bf16_1k(a, b, c, 0, 0, 0);
#else
    f4 d;
    asm("v_mfma_f32_16x16x16_bf16 %0, %1, %2, %3" : "=v"(d) : "v"(a), "v"(b), "v"(c));
    return d;
#endif
}

// ---------------- fused prep: K and V -> bf16 lane-linear tile layouts ----------------
// K tile (b,kt)=4KB: chunk p = s*64 + g*16 + c (s=t+2h) holds
//   K[b][kt*32+16t+c][32h+8g+j], j=0..7  -> lane l's QK frags at chunks l,64+l,128+l,192+l.
// V tile (b,kt)=4KB: chunk p = vb*64 + g*16 + c holds, for v=16vb+c:
//   [t=0: V[kt*32+4g+j][v] j=0..3][t=1: V[kt*32+16+4g+j][v]] -> lane l at chunks vb*64+l.
__global__ __launch_bounds__(256) void kv_retile(const float* __restrict__ K,
                                                 const float* __restrict__ V,
                                                 unsigned short* __restrict__ KbT,
                                                 unsigned short* __restrict__ VtT) {
    if (blockIdx.x < 1024) {
        int b = blockIdx.x >> 6, kt = blockIdx.x & 63;
        int p = threadIdx.x;
        int s = p >> 6, g = (p >> 4) & 3, c = p & 15;
        int t = s & 1, h = s >> 1;
        const float* src = K + ((size_t)(b * SK_ + kt * 32 + 16 * t + c)) * D_ + 32 * h + 8 * g;
        f4 a = *(const f4*)src;
        f4 b2 = *(const f4*)(src + 4);
        u32x4 w;
        w[0] = pk2(a.x, a.y); w[1] = pk2(a.z, a.w);
        w[2] = pk2(b2.x, b2.y); w[3] = pk2(b2.z, b2.w);
        *(u32x4*)(KbT + ((size_t)(b * 64 + kt)) * 2048 + (size_t)p * 8) = w;
    } else {
        __shared__ float vt[32][65];
        int id = blockIdx.x - 1024;
        int b = id >> 6, kt = id & 63;
        int tid = threadIdx.x;
#pragma unroll
        for (int e = 0; e < 2; ++e) {
            int f = tid * 2 + e;
            int row = f >> 4, c4 = (f & 15) * 4;
            *(f4*)&vt[row][c4] = *(const f4*)(V + ((size_t)(b * SK_ + kt * 32 + row)) * DV_ + c4);
        }
        __syncthreads();
        int vb = tid >> 6, g = (tid >> 4) & 3, c = tid & 15;
        int v = vb * 16 + c;
        u32x4 w;
        w[0] = pk2(vt[4 * g + 0][v], vt[4 * g + 1][v]);
        w[1] = pk2(vt[4 * g + 2][v], vt[4 * g + 3][v]);
        w[2] = pk2(vt[16 + 4 * g + 0][v], vt[16 + 4 * g + 1][v]);
        w[3] = pk2(vt[16 + 4 * g + 2][v], vt[16 + 4 * g + 3][v]);
        *(u32x4*)(VtT + ((size_t)(b * 64 + kt)) * 2048 + (size_t)tid * 8) = w;
    }
}

// ---------------- main fused attention kernel ----------------
// FULLY DECOUPLED WAVES: no LDS, no barriers. Each wave owns one
// (16-q-strip x k-range) task; K/V/mask live in REGISTER rings filled by
// volatile-asm global_load_dwordx4 (cannot be sunk — the R2/R3 failure mode).
// K/V ring-2 (L2-resident after first touch), mask ring-4 (HBM, 3-tile lead).
// Per tile issue [KV(kt+1), M(kt+3)]; uniform vmcnt(12) completes exactly
// KV(kt)+M(kt) (FIFO-verified incl. prologue M0,M1,KV0,M2). Any wave stall
// is filled by ~11 other independent waves/CU — fill-kernel-style TLP.
// Swapped QK^T (16x16x32, log2e folded into Q), transposed PV (16x16x16,
// B-op = QK^T C-layout) -> zero cross-lane ops. No max subtraction (scores
// ~N(0,1), f32-safe); l lane-local; 1/0.9 folded at the end.
template <int SPLIT>
__global__ __launch_bounds__(256) void attn_main(const float* __restrict__ Q,
                                                 const unsigned short* __restrict__ KbT,
                                                 const unsigned short* __restrict__ VtT,
                                                 const float* __restrict__ mask,
                                                 float* __restrict__ out,
                                                 float* __restrict__ accP,
                                                 float* __restrict__ lP) {
    constexpr int NT32 = SK_ / SPLIT / 32;     // 32-k tiles per wave
    constexpr int NB = 512 * SPLIT;

    int bswz = (blockIdx.x & 7) * (NB / 8) + (blockIdx.x >> 3);
    int wid  = threadIdx.x >> 6;
    int split = bswz & (SPLIT - 1);
    int strip = (bswz / SPLIT) * 4 + wid;
    int b  = strip >> 7;
    int q0 = (strip & 127) << 4;
    int kb = split * (SK_ / SPLIT);
    int lane = threadIdx.x & 63;
    int g = lane >> 4, c = lane & 15;

    const size_t tile0 = ((size_t)b * 64 + split * NT32) * 2048;
    const unsigned short* ksrc = KbT + tile0 + (size_t)lane * 8;
    const unsigned short* vsrc = VtT + tile0 + (size_t)lane * 8;
    const float* msrc = mask + ((size_t)(b * SQ_ + q0 + c)) * SK_ + kb + 4 * g;

    // Q fragments; consumed (packed) before the staging stream starts
    bf16x8 qf[2];
    {
        const float* qp = Q + ((size_t)(b * SQ_ + q0 + c)) * D_ + 8 * g;
#pragma unroll
        for (int h = 0; h < 2; ++h) {
            f4 a  = *(const f4*)(qp + h * 32);
            f4 bq = *(const f4*)(qp + h * 32 + 4);
            u32x4 wq;
            wq[0] = pk2(a.x * QSCALE, a.y * QSCALE);
            wq[1] = pk2(a.z * QSCALE, a.w * QSCALE);
            wq[2] = pk2(bq.x * QSCALE, bq.y * QSCALE);
            wq[3] = pk2(bq.z * QSCALE, bq.w * QSCALE);
            qf[h] = __builtin_bit_cast(bf16x8, wq);
        }
    }
    __builtin_amdgcn_sched_barrier(0);

    // register rings (all indices compile-time via unroll 4)
    u32x4 kr[2][4];   // [slot][0]=t0,d0-31  [1]=t1,d0-31  [2]=t0,d32-63  [3]=t1,d32-63
    u32x4 vr[2][4];   // [slot][vb]
    f4    mr[4][2];   // [slot][t]

    auto kvload = [&](int slot, int srct) {
        const unsigned short* kp = ksrc + (size_t)srct * 2048;
        kr[slot][0] = gload_u4<0>(kp);
        kr[slot][1] = gload_u4<1024>(kp);
        kr[slot][2] = gload_u4<2048>(kp);
        kr[slot][3] = gload_u4<3072>(kp);
        const unsigned short* vp = vsrc + (size_t)srct * 2048;
        vr[slot][0] = gload_u4<0>(vp);
        vr[slot][1] = gload_u4<1024>(vp);
        vr[slot][2] = gload_u4<2048>(vp);
        vr[slot][3] = gload_u4<3072>(vp);
    };
    auto mload = [&](int slot, int srct) {
        const float* mp = msrc + (size_t)srct * 32;
        mr[slot][0] = gload_f4<0>(mp);
        mr[slot][1] = gload_f4<64>(mp);
    };

    // prologue (oldest->youngest): M0 M1 KV0 M2   (14 ops)
    mload(0, 0);
    mload(1, 1);
    kvload(0, 0);
    mload(2, 2);

    f4 acc[4];
#pragma unroll
    for (int vb = 0; vb < 4; ++vb) acc[vb] = (f4){0.f, 0.f, 0.f, 0.f};
    f4 ls0 = (f4){0.f, 0.f, 0.f, 0.f}, ls1 = (f4){0.f, 0.f, 0.f, 0.f};

#pragma unroll 4
    for (int kt = 0; kt < NT32; ++kt) {
        // issue next: KV(kt+1) then M(kt+3); clamped dummies keep counts uniform
        kvload((kt + 1) & 1, (kt + 1 < NT32) ? kt + 1 : NT32 - 1);
        mload((kt + 3) & 3, (kt + 3 < NT32) ? kt + 3 : NT32 - 1);
        // newest 12 = M(kt+2),KV(kt+1),M(kt+3) -> everything for tile kt done
        asm volatile("s_waitcnt vmcnt(12)" ::: "memory");
        __builtin_amdgcn_sched_barrier(0);

        const int ks = kt & 1, ms = kt & 3;

        // QK^T: S^T rows k_local = 16t + 4g + r, col q = c (values = s*log2e)
        f4 st0 = (f4){0.f, 0.f, 0.f, 0.f}, st1 = (f4){0.f, 0.f, 0.f, 0.f};
        st0 = __builtin_amdgcn_mfma_f32_16x16x32_bf16(__builtin_bit_cast(bf16x8, kr[ks][0]), qf[0], st0, 0, 0, 0);
        st0 = __builtin_amdgcn_mfma_f32_16x16x32_bf16(__builtin_bit_cast(bf16x8, kr[ks][2]), qf[1], st0, 0, 0, 0);
        st1 = __builtin_amdgcn_mfma_f32_16x16x32_bf16(__builtin_bit_cast(bf16x8, kr[ks][1]), qf[0], st1, 0, 0, 0);
        st1 = __builtin_amdgcn_mfma_f32_16x16x32_bf16(__builtin_bit_cast(bf16x8, kr[ks][3]), qf[1], st1, 0, 0, 0);

        // p = exp2(st) = exp(s); lane-local l; register-mask-gated dropout
        const f4 mk0 = mr[ms][0], mk1 = mr[ms][1];
        float pd0[4], pd1[4];
#pragma unroll
        for (int r = 0; r < 4; ++r) {
            float p0 = fexp2(st0[r]);
            ls0[r] += p0;
            pd0[r] = (mk0[r] > 0.1f) ? p0 : 0.f;
            float p1 = fexp2(st1[r]);
            ls1[r] += p1;
            pd1[r] = (mk1[r] > 0.1f) ? p1 : 0.f;
        }

        // PV (transposed): O^T[v][q] += V^T[v][k] * P^T[k][q]
        u32x2 pw0, pw1;
        pw0[0] = pkc(pd0[0], pd0[1]); pw0[1] = pkc(pd0[2], pd0[3]);
        pw1[0] = pkc(pd1[0], pd1[1]); pw1[1] = pkc(pd1[2], pd1[3]);
        s16x4 pb0 = __builtin_bit_cast(s16x4, pw0);
        s16x4 pb1 = __builtin_bit_cast(s16x4, pw1);
#pragma unroll
        for (int vb = 0; vb < 4; ++vb) {
            u32x4 vv = vr[ks][vb];
            u32x2 vlo, vhi;
            vlo[0] = vv[0]; vlo[1] = vv[1];
            vhi[0] = vv[2]; vhi[1] = vv[3];
            acc[vb] = mfma16(__builtin_bit_cast(s16x4, vlo), pb0, acc[vb]);
            acc[vb] = mfma16(__builtin_bit_cast(s16x4, vhi), pb1, acc[vb]);
        }
    }
    asm volatile("s_waitcnt vmcnt(0)" ::: "memory");   // drain clamped dummies
    __builtin_amdgcn_sched_barrier(0);

    // l reduce: lane-local partials -> per-column (q=c) total
    float lf = ls0[0] + ls0[1] + ls0[2] + ls0[3] + ls1[0] + ls1[1] + ls1[2] + ls1[3];
    lf += __shfl_xor(lf, 16);
    lf += __shfl_xor(lf, 32);   // lf = l(q=c) on every lane

    if constexpr (SPLIT == 1) {
        float li = INV_KEEP / lf;
        float* op = out + ((size_t)(b * SQ_ + q0 + c)) * DV_;
#pragma unroll
        for (int vb = 0; vb < 4; ++vb) {
            f4 o = acc[vb] * li;
            __builtin_nontemporal_store(o, (f4*)(op + 16 * vb + 4 * g));
        }
    } else {
        // lane-major partial: slot 4*vb+r = O^T[v=16vb+4g+r][q=c]
        float* ap = accP + (((size_t)strip * SPLIT + split) * 64 + lane) * 16;
#pragma unroll
        for (int vb = 0; vb < 4; ++vb)
            *(f4*)(ap + 4 * vb) = acc[vb];
        if (g == 0)
            lP[((size_t)strip * SPLIT + split) * 16 + c] = lf;
    }
}

// ---------------- combine kernel (SPLIT=2 path) ----------------
__global__ __launch_bounds__(256) void attn_combine2(const float* __restrict__ accP,
                                                     const float* __restrict__ lP,
                                                     float* __restrict__ out) {
    __shared__ float sacc[2 * 1280];   // 2 splits x 64 lanes x 16 slots, stride 20
    __shared__ float sl[32];
    int strip = blockIdx.x;
    int t = threadIdx.x;
    const float* src = accP + (size_t)strip * 2048;
#pragma unroll
    for (int s = 0; s < 2; ++s)
        *(f4*)&sacc[s * 1280 + (t >> 2) * 20 + (t & 3) * 4] = *(const f4*)(src + s * 1024 + t * 4);
    if (t < 32) sl[t] = lP[(size_t)strip * 32 + t];
    __syncthreads();

    int q = t >> 4, j = t & 15;        // output row q, f4-column j (v = 4j..4j+3)
    float L = sl[q] + sl[16 + q];
    float inv = INV_KEEP / L;
    // v = 4j+i -> lane = 16*(j&3)+q, slot = 4*(j>>2)+i
    int base = (16 * (j & 3) + q) * 20 + 4 * (j >> 2);
    f4 o = *(const f4*)&sacc[base] + *(const f4*)&sacc[1280 + base];
    o *= inv;
    int b  = strip >> 7;
    int q0 = (strip & 127) << 4;
    __builtin_nontemporal_store(o, (f4*)(out + ((size_t)(b * SQ_ + q0 + q)) * DV_ + 4 * j));
}

extern "C" void kernel_launch(void* const* d_in, const int* in_sizes, int n_in,
                              void* d_out, int out_size, void* d_ws, size_t ws_size,
                              hipStream_t stream) {
    const float* Q = (const float*)d_in[0];
    const float* K = (const float*)d_in[1];
    const float* V = (const float*)d_in[2];
    const float* M = (const float*)d_in[3];
    float* out = (float*)d_out;

    char* ws = (char*)d_ws;
    unsigned short* KbT  = (unsigned short*)ws;                               // 4 MB
    unsigned short* VtT  = (unsigned short*)(ws + (size_t)4 * 1024 * 1024);   // 4 MB
    float*          accP = (float*)         (ws + (size_t)8 * 1024 * 1024);   // 16 MB
    float*          lP   = (float*)         (ws + (size_t)24 * 1024 * 1024);  // 256 KB

    const size_t need_split = (size_t)24 * 1024 * 1024 + (size_t)2048 * 2 * 16 * 4;

    kv_retile<<<2048, 256, 0, stream>>>(K, V, KbT, VtT);
    if (ws_size >= need_split) {
        attn_main<2><<<1024, 256, 0, stream>>>(Q, KbT, VtT, M, out, accP, lP);
        attn_combine2<<<2048, 256, 0, stream>>>(accP, lP, out);
    } else {
        attn_main<1><<<512, 256, 0, stream>>>(Q, KbT, VtT, M, out, nullptr, nullptr);
    }
}